// Round 1
// baseline (474.331 us; speedup 1.0000x reference)
//
#include <hip/hip_runtime.h>
#include <cstddef>

// B=8192 trees, 16 leaves + 1 root each. FEAT=480 (14 tokens x 16 embed + 256 lstm).
// Kernel 1: fused gather + MLP (480->128 relu ->32 relu) for all leaf rows (blocks 0..1023)
//           and node rows (blocks 1024..1087). f32, LDS-tiled, register-blocked.
// Kernel 2: per-block 32-tree sequential scan (15 steps of 64->128->32 MLP) + combine MLP
//           + fused final linear (dot with precomputed v, + c0).

__global__ __launch_bounds__(256) void mlp1_kernel(
    const int* __restrict__ trees,
    const float* __restrict__ lstm,
    const float* __restrict__ embedding,
    const float* __restrict__ leaf_end_W,
    const float* __restrict__ leaf_end_b,
    const float* __restrict__ lc_W1, const float* __restrict__ lc_b1,
    const float* __restrict__ lc_W2, const float* __restrict__ lc_b2,
    const float* __restrict__ nf_W1, const float* __restrict__ nf_b1,
    const float* __restrict__ nf_W2, const float* __restrict__ nf_b2,
    float* __restrict__ children,
    float* __restrict__ node_tmp)
{
    __shared__ float emb_s[3200];        // 200 x 16 embedding table
    __shared__ float As[32][128];        // A chunk, transposed: As[kk][row]
    __shared__ float Ws[32][128];        // W1 chunk: Ws[kk][col]
    __shared__ float Hs[128][132];       // layer-1 output (padded)
    __shared__ float W2s[128 * 32];
    __shared__ float b1s[128];
    __shared__ float b2s[32];
    __shared__ float endvec[32];

    const int tid = threadIdx.x;
    const int blk = blockIdx.x;
    const bool leaf_mode = (blk < 1024);

    const float* __restrict__ W1p = leaf_mode ? lc_W1 : nf_W1;
    const float* __restrict__ b1p = leaf_mode ? lc_b1 : nf_b1;
    const float* __restrict__ W2p = leaf_mode ? lc_W2 : nf_W2;
    const float* __restrict__ b2p = leaf_mode ? lc_b2 : nf_b2;

    for (int i = tid; i < 3200; i += 256) emb_s[i] = embedding[i];
    for (int i = tid; i < 4096; i += 256) W2s[i] = W2p[i];
    if (tid < 128) b1s[tid] = b1p[tid];
    if (tid < 32)  b2s[tid] = b2p[tid];
    if (leaf_mode && tid < 32) {
        // children row for is_end leaves is constant: embedding[1] @ leaf_end_W + leaf_end_b
        float a = leaf_end_b[tid];
        #pragma unroll
        for (int d = 0; d < 16; ++d) a = fmaf(embedding[16 + d], leaf_end_W[d * 32 + tid], a);
        endvec[tid] = a;
    }

    // staging role: row m of this block's 128-row tile, half of the 32-wide K chunk
    const int m = tid & 127;
    const int half = tid >> 7;
    int b, trow;
    if (leaf_mode) { const int r = blk * 128 + m; b = r >> 4; trow = 1 + (r & 15); }
    else           { b = (blk - 1024) * 128 + m; trow = 0; }
    const int* __restrict__ ti = trees + (b * 17 + trow) * 17;
    const int ptr = ti[16];
    const float* __restrict__ lrow = lstm + ((size_t)b * 64 + (size_t)ptr) * 256;

    // compute role: 8 rows x 8 cols per thread
    const int rg = tid >> 4, cg = tid & 15;
    const int r0 = rg * 8, c0 = cg * 8;
    float acc[8][8];
    #pragma unroll
    for (int i = 0; i < 8; ++i)
        #pragma unroll
        for (int j = 0; j < 8; ++j) acc[i][j] = 0.f;

    __syncthreads();

    for (int k0 = 0; k0 < 480; k0 += 32) {
        // ---- stage A chunk (gathered feature columns k0..k0+31, transposed) ----
        const int kkb = half * 16;
        const int kbase = k0 + kkb;
        if (kbase < 224) {
            // embedding part: 16 consecutive dims of exactly one token
            const int tok = ti[2 + (kbase >> 4)];
            const float* __restrict__ e = &emb_s[tok * 16];
            #pragma unroll
            for (int j = 0; j < 16; ++j) As[kkb + j][m] = e[j];
        } else {
            const float* __restrict__ src = lrow + (kbase - 224);
            #pragma unroll
            for (int j4 = 0; j4 < 4; ++j4) {
                const float4 v = *(const float4*)(src + j4 * 4);
                As[kkb + j4 * 4 + 0][m] = v.x;
                As[kkb + j4 * 4 + 1][m] = v.y;
                As[kkb + j4 * 4 + 2][m] = v.z;
                As[kkb + j4 * 4 + 3][m] = v.w;
            }
        }
        // ---- stage W1 chunk ----
        {
            const float4* __restrict__ w4 = (const float4*)(W1p + k0 * 128);
            float4* __restrict__ d4 = (float4*)(&Ws[0][0]);
            #pragma unroll
            for (int j = 0; j < 4; ++j) d4[tid + 256 * j] = w4[tid + 256 * j];
        }
        __syncthreads();
        // ---- 128x128 outer-product accumulate over 32 k's ----
        #pragma unroll 4
        for (int kk = 0; kk < 32; ++kk) {
            const float4 a0 = *(const float4*)&As[kk][r0];
            const float4 a1 = *(const float4*)&As[kk][r0 + 4];
            const float4 w0 = *(const float4*)&Ws[kk][c0];
            const float4 w1 = *(const float4*)&Ws[kk][c0 + 4];
            const float av[8] = {a0.x, a0.y, a0.z, a0.w, a1.x, a1.y, a1.z, a1.w};
            const float wv[8] = {w0.x, w0.y, w0.z, w0.w, w1.x, w1.y, w1.z, w1.w};
            #pragma unroll
            for (int i = 0; i < 8; ++i)
                #pragma unroll
                for (int j = 0; j < 8; ++j)
                    acc[i][j] = fmaf(av[i], wv[j], acc[i][j]);
        }
        __syncthreads();
    }

    // bias + relu -> Hs
    #pragma unroll
    for (int i = 0; i < 8; ++i)
        #pragma unroll
        for (int j = 0; j < 8; ++j) {
            const float v = acc[i][j] + b1s[c0 + j];
            Hs[r0 + i][c0 + j] = v > 0.f ? v : 0.f;
        }
    __syncthreads();

    // ---- layer 2: 128 -> 32, 4 rows x 4 cols per thread ----
    const int rr = tid >> 3, cc = tid & 7;
    const int rb = rr * 4, c2 = cc * 4;
    float a2[4][4];
    #pragma unroll
    for (int i = 0; i < 4; ++i)
        #pragma unroll
        for (int j = 0; j < 4; ++j) a2[i][j] = b2s[c2 + j];
    for (int k = 0; k < 128; k += 4) {
        float hv[4][4];
        #pragma unroll
        for (int i = 0; i < 4; ++i) {
            const float4 h4 = *(const float4*)&Hs[rb + i][k];
            hv[i][0] = h4.x; hv[i][1] = h4.y; hv[i][2] = h4.z; hv[i][3] = h4.w;
        }
        #pragma unroll
        for (int kk = 0; kk < 4; ++kk) {
            const float4 w = *(const float4*)&W2s[(k + kk) * 32 + c2];
            const float wj[4] = {w.x, w.y, w.z, w.w};
            #pragma unroll
            for (int i = 0; i < 4; ++i)
                #pragma unroll
                for (int j = 0; j < 4; ++j)
                    a2[i][j] = fmaf(hv[i][kk], wj[j], a2[i][j]);
        }
    }

    if (leaf_mode) {
        #pragma unroll
        for (int i = 0; i < 4; ++i) {
            const int r = blk * 128 + rb + i;           // global leaf row = b*16 + leaf
            const int bb = r >> 4, lc = r & 15;
            const bool is_end = (trees[(bb * 17 + 1 + lc) * 17 + 2] == 1);
            float4 o;
            o.x = is_end ? endvec[c2 + 0] : fmaxf(a2[i][0], 0.f);
            o.y = is_end ? endvec[c2 + 1] : fmaxf(a2[i][1], 0.f);
            o.z = is_end ? endvec[c2 + 2] : fmaxf(a2[i][2], 0.f);
            o.w = is_end ? endvec[c2 + 3] : fmaxf(a2[i][3], 0.f);
            *(float4*)&children[(size_t)r * 32 + c2] = o;
        }
    } else {
        #pragma unroll
        for (int i = 0; i < 4; ++i) {
            const int bb = (blk - 1024) * 128 + rb + i;
            float4 o;
            o.x = fmaxf(a2[i][0], 0.f);
            o.y = fmaxf(a2[i][1], 0.f);
            o.z = fmaxf(a2[i][2], 0.f);
            o.w = fmaxf(a2[i][3], 0.f);
            *(float4*)&node_tmp[(size_t)bb * 32 + c2] = o;
        }
    }
}

__global__ __launch_bounds__(512) void scan_kernel(
    const float* __restrict__ children,
    const float* __restrict__ node_tmp,
    const float* __restrict__ cs_W1, const float* __restrict__ cs_b1,
    const float* __restrict__ cs_W2, const float* __restrict__ cs_b2,
    const float* __restrict__ cb_W1, const float* __restrict__ cb_b1,
    const float* __restrict__ cb_W2, const float* __restrict__ cb_b2,
    const float* __restrict__ ff_W1, const float* __restrict__ ff_b1,
    const float* __restrict__ ff_W2, const float* __restrict__ ff_b2,
    const float* __restrict__ ts_W, const float* __restrict__ ts_b,
    float* __restrict__ out)
{
    __shared__ float W1a[64 * 128];   // cs_W1
    __shared__ float W2a[128 * 32];   // cs_W2
    __shared__ float W1b[64 * 128];   // cb_W1
    __shared__ float W2b[128 * 32];   // cb_W2
    __shared__ float b1a[128], b2a[32], b1b[128], b2b[32];
    __shared__ float Xs[32][66];      // [carry | child] per tree (padded: 2-way only)
    __shared__ float Hs[32][134];     // hidden per tree (padded)
    __shared__ float vfin[32];
    __shared__ float cfin_s;

    const int tid = threadIdx.x;
    {
        const float4* s; float4* d;
        s = (const float4*)cs_W1; d = (float4*)W1a;
        for (int i = tid; i < 2048; i += 512) d[i] = s[i];
        s = (const float4*)cs_W2; d = (float4*)W2a;
        for (int i = tid; i < 1024; i += 512) d[i] = s[i];
        s = (const float4*)cb_W1; d = (float4*)W1b;
        for (int i = tid; i < 2048; i += 512) d[i] = s[i];
        s = (const float4*)cb_W2; d = (float4*)W2b;
        for (int i = tid; i < 1024; i += 512) d[i] = s[i];
    }
    if (tid < 128) { b1a[tid] = cs_b1[tid]; b1b[tid] = cb_b1[tid]; }
    else if (tid < 160) { b2a[tid - 128] = cs_b2[tid - 128]; b2b[tid - 128] = cb_b2[tid - 128]; }
    if (tid >= 256 && tid < 288) {
        // final linear chain collapses: out = tree_sum . vfin + cfin
        const int c = tid - 256;
        float a = 0.f;
        for (int k = 0; k < 32; ++k) {
            float w2t = 0.f;
            for (int j = 0; j < 32; ++j) w2t = fmaf(ff_W2[k * 32 + j], ts_W[j], w2t);
            a = fmaf(ff_W1[c * 32 + k], w2t, a);
        }
        vfin[c] = a;
    }
    if (tid == 511) {
        float a = ts_b[0];
        for (int j = 0; j < 32; ++j) a = fmaf(ff_b2[j], ts_W[j], a);
        for (int k = 0; k < 32; ++k) {
            float w2t = 0.f;
            for (int j = 0; j < 32; ++j) w2t = fmaf(ff_W2[k * 32 + j], ts_W[j], w2t);
            a = fmaf(ff_b1[k], w2t, a);
        }
        cfin_s = a;
    }

    const int t = tid & 31, g = tid >> 5;       // tree-in-block, column group
    const size_t base = (size_t)blockIdx.x * 32;

    // init carry = children[tree][0]
    #pragma unroll
    for (int u = 0; u < 2; ++u) {
        const int e = tid + u * 512;
        const int tt = e >> 5, c = e & 31;
        Xs[tt][c] = children[((base + tt) * 16 + 0) * 32 + c];
    }
    __syncthreads();

    for (int it = 1; it <= 16; ++it) {
        const bool fin = (it == 16);
        if (!fin) {
            #pragma unroll
            for (int u = 0; u < 2; ++u) {
                const int e = tid + u * 512;
                const int tt = e >> 5, c = e & 31;
                Xs[tt][32 + c] = children[((base + tt) * 16 + it) * 32 + c];
            }
        } else {
            // combine step: input = [node_tmp | child_summary]
            float sv[2];
            #pragma unroll
            for (int u = 0; u < 2; ++u) {
                const int e = tid + u * 512;
                sv[u] = Xs[e >> 5][e & 31];
            }
            __syncthreads();
            #pragma unroll
            for (int u = 0; u < 2; ++u) {
                const int e = tid + u * 512;
                const int tt = e >> 5, c = e & 31;
                Xs[tt][32 + c] = sv[u];
                Xs[tt][c] = node_tmp[(base + tt) * 32 + c];
            }
        }
        __syncthreads();

        const float* __restrict__ W1c = fin ? W1b : W1a;
        const float* __restrict__ W2c = fin ? W2b : W2a;
        const float* __restrict__ b1c = fin ? b1b : b1a;
        const float* __restrict__ b2c = fin ? b2b : b2a;

        // layer 1: 64 -> 128, 8 cols per thread
        {
            const int c0 = g * 8;
            float h[8];
            #pragma unroll
            for (int j = 0; j < 8; ++j) h[j] = b1c[c0 + j];
            #pragma unroll 4
            for (int k = 0; k < 64; k += 2) {
                const float2 xv = *(const float2*)&Xs[t][k];
                const float4 w00 = *(const float4*)&W1c[k * 128 + c0];
                const float4 w01 = *(const float4*)&W1c[k * 128 + c0 + 4];
                const float4 w10 = *(const float4*)&W1c[(k + 1) * 128 + c0];
                const float4 w11 = *(const float4*)&W1c[(k + 1) * 128 + c0 + 4];
                h[0] = fmaf(xv.x, w00.x, h[0]); h[1] = fmaf(xv.x, w00.y, h[1]);
                h[2] = fmaf(xv.x, w00.z, h[2]); h[3] = fmaf(xv.x, w00.w, h[3]);
                h[4] = fmaf(xv.x, w01.x, h[4]); h[5] = fmaf(xv.x, w01.y, h[5]);
                h[6] = fmaf(xv.x, w01.z, h[6]); h[7] = fmaf(xv.x, w01.w, h[7]);
                h[0] = fmaf(xv.y, w10.x, h[0]); h[1] = fmaf(xv.y, w10.y, h[1]);
                h[2] = fmaf(xv.y, w10.z, h[2]); h[3] = fmaf(xv.y, w10.w, h[3]);
                h[4] = fmaf(xv.y, w11.x, h[4]); h[5] = fmaf(xv.y, w11.y, h[5]);
                h[6] = fmaf(xv.y, w11.z, h[6]); h[7] = fmaf(xv.y, w11.w, h[7]);
            }
            #pragma unroll
            for (int j = 0; j < 8; ++j) Hs[t][c0 + j] = h[j] > 0.f ? h[j] : 0.f;
        }
        __syncthreads();
        // layer 2: 128 -> 32, 2 cols per thread; write result back into Xs[t][0..31]
        {
            const int c2 = g * 2;
            float o0 = b2c[c2], o1 = b2c[c2 + 1];
            #pragma unroll 4
            for (int k = 0; k < 128; k += 2) {
                const float2 hv = *(const float2*)&Hs[t][k];
                const float2 wA = *(const float2*)&W2c[k * 32 + c2];
                const float2 wB = *(const float2*)&W2c[(k + 1) * 32 + c2];
                o0 = fmaf(hv.x, wA.x, o0); o1 = fmaf(hv.x, wA.y, o1);
                o0 = fmaf(hv.y, wB.x, o0); o1 = fmaf(hv.y, wB.y, o1);
            }
            Xs[t][c2]     = o0 > 0.f ? o0 : 0.f;
            Xs[t][c2 + 1] = o1 > 0.f ? o1 : 0.f;
        }
        __syncthreads();
    }

    if (tid < 32) {
        float a = cfin_s;
        #pragma unroll
        for (int c = 0; c < 32; ++c) a = fmaf(Xs[tid][c], vfin[c], a);
        out[base + tid] = a;
    }
}

extern "C" void kernel_launch(void* const* d_in, const int* in_sizes, int n_in,
                              void* d_out, int out_size, void* d_ws, size_t ws_size,
                              hipStream_t stream) {
    const int*   trees      = (const int*)d_in[0];
    const float* lstm       = (const float*)d_in[1];
    // d_in[2] = first_notes (unused), d_in[3] = train (unused)
    const float* embedding  = (const float*)d_in[4];
    const float* leaf_end_W = (const float*)d_in[5];
    const float* leaf_end_b = (const float*)d_in[6];
    const float* lc_W1 = (const float*)d_in[7];
    const float* lc_b1 = (const float*)d_in[8];
    const float* lc_W2 = (const float*)d_in[9];
    const float* lc_b2 = (const float*)d_in[10];
    const float* cs_W1 = (const float*)d_in[11];
    const float* cs_b1 = (const float*)d_in[12];
    const float* cs_W2 = (const float*)d_in[13];
    const float* cs_b2 = (const float*)d_in[14];
    const float* nf_W1 = (const float*)d_in[15];
    const float* nf_b1 = (const float*)d_in[16];
    const float* nf_W2 = (const float*)d_in[17];
    const float* nf_b2 = (const float*)d_in[18];
    const float* cb_W1 = (const float*)d_in[19];
    const float* cb_b1 = (const float*)d_in[20];
    const float* cb_W2 = (const float*)d_in[21];
    const float* cb_b2 = (const float*)d_in[22];
    const float* ff_W1 = (const float*)d_in[23];
    const float* ff_b1 = (const float*)d_in[24];
    const float* ff_W2 = (const float*)d_in[25];
    const float* ff_b2 = (const float*)d_in[26];
    const float* ts_W  = (const float*)d_in[27];
    const float* ts_b  = (const float*)d_in[28];

    float* children = (float*)d_ws;                                   // 8192*16*32 f32 = 16 MiB
    float* node_tmp = (float*)((char*)d_ws + (size_t)8192 * 16 * 32 * 4);  // + 1 MiB
    float* outp = (float*)d_out;

    mlp1_kernel<<<dim3(1088), dim3(256), 0, stream>>>(
        trees, lstm, embedding, leaf_end_W, leaf_end_b,
        lc_W1, lc_b1, lc_W2, lc_b2, nf_W1, nf_b1, nf_W2, nf_b2,
        children, node_tmp);

    scan_kernel<<<dim3(256), dim3(512), 0, stream>>>(
        children, node_tmp,
        cs_W1, cs_b1, cs_W2, cs_b2, cb_W1, cb_b1, cb_W2, cb_b2,
        ff_W1, ff_b1, ff_W2, ff_b2, ts_W, ts_b, outp);
}

// Round 2
// 200.056 us; speedup vs baseline: 2.3710x; 2.3710x over previous
//
#include <hip/hip_runtime.h>
#include <cstddef>

// B=8192 trees, 16 leaves + 1 root. FEAT=480 (14 tok x 16 emb + 256 lstm).
// prep_kernel:  transpose+bf16-convert W1 (480x128 -> [128][480]) and W2
//               (128x32 -> [32][128]) for lc/nf, bf16 embedding, endvec.
// mlp1_mfma:    fused gather + MFMA MLP (480->128 relu ->32 relu) for leaf rows
//               (blocks 0..1023) and node rows (1024..1087). bf16 in, f32 acc.
// scan_kernel:  per-block 32-tree sequential scan (15 steps 64->128->32) +
//               combine MLP + collapsed final linear. f32 (unchanged, correct).

typedef __bf16 bf16x8 __attribute__((ext_vector_type(8)));
typedef float  f32x4  __attribute__((ext_vector_type(4)));

__global__ __launch_bounds__(256) void prep_kernel(
    const float* __restrict__ embedding,
    const float* __restrict__ leaf_end_W, const float* __restrict__ leaf_end_b,
    const float* __restrict__ lc_W1, const float* __restrict__ lc_W2,
    const float* __restrict__ nf_W1, const float* __restrict__ nf_W2,
    __bf16* __restrict__ lcW1T, __bf16* __restrict__ nfW1T,
    __bf16* __restrict__ lcW2T, __bf16* __restrict__ nfW2T,
    __bf16* __restrict__ emb_bf, float* __restrict__ endvec)
{
    const int id = blockIdx.x * 256 + threadIdx.x;
    if (id < 61440) {                       // lcW1T[n][k] = lc_W1[k][n]
        const int n = id / 480, k = id - n * 480;
        lcW1T[id] = (__bf16)lc_W1[k * 128 + n];
    } else if (id < 122880) {
        const int e = id - 61440;
        const int n = e / 480, k = e - n * 480;
        nfW1T[e] = (__bf16)nf_W1[k * 128 + n];
    } else if (id < 126976) {               // lcW2T[n][k] = lc_W2[k][n]
        const int e = id - 122880;
        const int n = e / 128, k = e - n * 128;
        lcW2T[e] = (__bf16)lc_W2[k * 32 + n];
    } else if (id < 131072) {
        const int e = id - 126976;
        const int n = e / 128, k = e - n * 128;
        nfW2T[e] = (__bf16)nf_W2[k * 32 + n];
    } else if (id < 134272) {
        emb_bf[id - 131072] = (__bf16)embedding[id - 131072];
    } else if (id < 134304) {               // endvec = emb[1] @ leaf_end_W + b (f32, no relu)
        const int c = id - 134272;
        float a = leaf_end_b[c];
        #pragma unroll
        for (int d = 0; d < 16; ++d) a = fmaf(embedding[16 + d], leaf_end_W[d * 32 + c], a);
        endvec[c] = a;
    }
}

__global__ __launch_bounds__(256) void mlp1_mfma(
    const int* __restrict__ trees,
    const float* __restrict__ lstm,
    const __bf16* __restrict__ lcW1T, const __bf16* __restrict__ nfW1T,
    const __bf16* __restrict__ lcW2T, const __bf16* __restrict__ nfW2T,
    const __bf16* __restrict__ emb_bf, const float* __restrict__ endvec,
    const float* __restrict__ lc_b1, const float* __restrict__ lc_b2,
    const float* __restrict__ nf_b1, const float* __restrict__ nf_b2,
    float* __restrict__ children,
    float* __restrict__ node_tmp)
{
    __shared__ __align__(16) __bf16 emb_s[3200];     // 6.4 KB
    __shared__ __align__(16) __bf16 Hs[128][136];    // 34.8 KB, padded stride
    __shared__ float b1s[128], b2s[32], evs[32];
    __shared__ int   endf[128];

    const int tid = threadIdx.x;
    const int blk = blockIdx.x;
    const bool leaf = (blk < 1024);

    const __bf16* __restrict__ W1T = leaf ? lcW1T : nfW1T;
    const __bf16* __restrict__ W2T = leaf ? lcW2T : nfW2T;
    const float*  __restrict__ b1p = leaf ? lc_b1 : nf_b1;
    const float*  __restrict__ b2p = leaf ? lc_b2 : nf_b2;

    for (int i = tid; i < 3200; i += 256) emb_s[i] = emb_bf[i];
    if (tid < 128) b1s[tid] = b1p[tid];
    if (tid < 32)  { b2s[tid] = b2p[tid]; evs[tid] = leaf ? endvec[tid] : 0.f; }
    if (tid < 128) {
        if (leaf) {
            const int R = blk * 128 + tid;
            const int b = R >> 4, trow = 1 + (R & 15);
            endf[tid] = (trees[(b * 17 + trow) * 17 + 2] == 1);
        } else endf[tid] = 0;
    }

    const int l  = tid & 63;
    const int w  = tid >> 6;        // wave 0..3
    const int wm = w >> 1;          // row half
    const int wn = w & 1;           // col half
    const int lm = l & 15;
    const int kb = l >> 4;          // k-block 0..3 (8 k's each)

    // per-row-tile tree/lstm base pointers for this lane's gather row
    const int* tb[4];
    const float* lb[4];
    #pragma unroll
    for (int rt = 0; rt < 4; ++rt) {
        const int r = wm * 64 + rt * 16 + lm;
        int b, trow;
        if (leaf) { const int R = blk * 128 + r; b = R >> 4; trow = 1 + (R & 15); }
        else      { b = (blk - 1024) * 128 + r; trow = 0; }
        const int* t = trees + (b * 17 + trow) * 17;
        tb[rt] = t;
        lb[rt] = lstm + ((size_t)b * 64 + (size_t)t[16]) * 256;
    }

    f32x4 acc[4][4];
    #pragma unroll
    for (int i = 0; i < 4; ++i)
        #pragma unroll
        for (int j = 0; j < 4; ++j) acc[i][j] = (f32x4){0.f, 0.f, 0.f, 0.f};

    __syncthreads();

    // ---- layer 1: 480 -> 128, K in 15 chunks of 32 ----
    #pragma unroll
    for (int c = 0; c < 15; ++c) {
        bf16x8 bfr[4];
        #pragma unroll
        for (int ct = 0; ct < 4; ++ct) {
            const int n = wn * 64 + ct * 16 + lm;
            bfr[ct] = *(const bf16x8*)(W1T + n * 480 + c * 32 + kb * 8);
        }
        bf16x8 afr[4];
        if (c < 7) {   // embedding chunks: k = 32c + 8kb -> token 2c + (kb>>1), dim offset 8*(kb&1)
            #pragma unroll
            for (int rt = 0; rt < 4; ++rt) {
                const int tok = tb[rt][2 + 2 * c + (kb >> 1)];
                afr[rt] = *(const bf16x8*)(emb_s + tok * 16 + (kb & 1) * 8);
            }
        } else {       // lstm chunks
            #pragma unroll
            for (int rt = 0; rt < 4; ++rt) {
                const float* p = lb[rt] + (c - 7) * 32 + kb * 8;
                const float4 u = *(const float4*)p;
                const float4 v = *(const float4*)(p + 4);
                bf16x8 t;
                t[0] = (__bf16)u.x; t[1] = (__bf16)u.y; t[2] = (__bf16)u.z; t[3] = (__bf16)u.w;
                t[4] = (__bf16)v.x; t[5] = (__bf16)v.y; t[6] = (__bf16)v.z; t[7] = (__bf16)v.w;
                afr[rt] = t;
            }
        }
        #pragma unroll
        for (int rt = 0; rt < 4; ++rt)
            #pragma unroll
            for (int ct = 0; ct < 4; ++ct)
                acc[rt][ct] = __builtin_amdgcn_mfma_f32_16x16x32_bf16(afr[rt], bfr[ct], acc[rt][ct], 0, 0, 0);
    }

    // bias + relu -> Hs (bf16). D layout: row = 4*kb + reg, col = lm (within 16x16 tile)
    #pragma unroll
    for (int rt = 0; rt < 4; ++rt)
        #pragma unroll
        for (int ct = 0; ct < 4; ++ct) {
            const int col = wn * 64 + ct * 16 + lm;
            const float bias = b1s[col];
            #pragma unroll
            for (int rg = 0; rg < 4; ++rg) {
                float v = acc[rt][ct][rg] + bias;
                v = v > 0.f ? v : 0.f;
                Hs[wm * 64 + rt * 16 + 4 * kb + rg][col] = (__bf16)v;
            }
        }
    __syncthreads();

    // ---- layer 2: 128 -> 32, wave w owns row-tiles {2w, 2w+1} x col-tiles {0,1} ----
    f32x4 acc2[2][2];
    #pragma unroll
    for (int i = 0; i < 2; ++i)
        #pragma unroll
        for (int j = 0; j < 2; ++j) acc2[i][j] = (f32x4){0.f, 0.f, 0.f, 0.f};

    #pragma unroll
    for (int kc = 0; kc < 4; ++kc) {
        bf16x8 a2f[2], b2f[2];
        #pragma unroll
        for (int i = 0; i < 2; ++i) {
            const int row = (2 * w + i) * 16 + lm;
            a2f[i] = *(const bf16x8*)(&Hs[row][kc * 32 + kb * 8]);
            const int n = i * 16 + lm;
            b2f[i] = *(const bf16x8*)(W2T + n * 128 + kc * 32 + kb * 8);
        }
        #pragma unroll
        for (int i = 0; i < 2; ++i)
            #pragma unroll
            for (int j = 0; j < 2; ++j)
                acc2[i][j] = __builtin_amdgcn_mfma_f32_16x16x32_bf16(a2f[i], b2f[j], acc2[i][j], 0, 0, 0);
    }

    #pragma unroll
    for (int i = 0; i < 2; ++i)
        #pragma unroll
        for (int j = 0; j < 2; ++j) {
            const int col = j * 16 + lm;
            const float bias = b2s[col];
            #pragma unroll
            for (int rg = 0; rg < 4; ++rg) {
                const int row = (2 * w + i) * 16 + 4 * kb + rg;
                float v = acc2[i][j][rg] + bias;
                v = v > 0.f ? v : 0.f;
                if (leaf) {
                    const size_t R = (size_t)blk * 128 + row;
                    children[R * 32 + col] = endf[row] ? evs[col] : v;
                } else {
                    const size_t R = (size_t)(blk - 1024) * 128 + row;
                    node_tmp[R * 32 + col] = v;
                }
            }
        }
}

__global__ __launch_bounds__(512) void scan_kernel(
    const float* __restrict__ children,
    const float* __restrict__ node_tmp,
    const float* __restrict__ cs_W1, const float* __restrict__ cs_b1,
    const float* __restrict__ cs_W2, const float* __restrict__ cs_b2,
    const float* __restrict__ cb_W1, const float* __restrict__ cb_b1,
    const float* __restrict__ cb_W2, const float* __restrict__ cb_b2,
    const float* __restrict__ ff_W1, const float* __restrict__ ff_b1,
    const float* __restrict__ ff_W2, const float* __restrict__ ff_b2,
    const float* __restrict__ ts_W, const float* __restrict__ ts_b,
    float* __restrict__ out)
{
    __shared__ float W1a[64 * 128];   // cs_W1
    __shared__ float W2a[128 * 32];   // cs_W2
    __shared__ float W1b[64 * 128];   // cb_W1
    __shared__ float W2b[128 * 32];   // cb_W2
    __shared__ float b1a[128], b2a[32], b1b[128], b2b[32];
    __shared__ float Xs[32][66];      // [carry | child] per tree
    __shared__ float Hs[32][134];     // hidden per tree
    __shared__ float vfin[32];
    __shared__ float cfin_s;

    const int tid = threadIdx.x;
    {
        const float4* s; float4* d;
        s = (const float4*)cs_W1; d = (float4*)W1a;
        for (int i = tid; i < 2048; i += 512) d[i] = s[i];
        s = (const float4*)cs_W2; d = (float4*)W2a;
        for (int i = tid; i < 1024; i += 512) d[i] = s[i];
        s = (const float4*)cb_W1; d = (float4*)W1b;
        for (int i = tid; i < 2048; i += 512) d[i] = s[i];
        s = (const float4*)cb_W2; d = (float4*)W2b;
        for (int i = tid; i < 1024; i += 512) d[i] = s[i];
    }
    if (tid < 128) { b1a[tid] = cs_b1[tid]; b1b[tid] = cb_b1[tid]; }
    else if (tid < 160) { b2a[tid - 128] = cs_b2[tid - 128]; b2b[tid - 128] = cb_b2[tid - 128]; }
    if (tid >= 256 && tid < 288) {
        const int c = tid - 256;
        float a = 0.f;
        for (int k = 0; k < 32; ++k) {
            float w2t = 0.f;
            for (int j = 0; j < 32; ++j) w2t = fmaf(ff_W2[k * 32 + j], ts_W[j], w2t);
            a = fmaf(ff_W1[c * 32 + k], w2t, a);
        }
        vfin[c] = a;
    }
    if (tid == 511) {
        float a = ts_b[0];
        for (int j = 0; j < 32; ++j) a = fmaf(ff_b2[j], ts_W[j], a);
        for (int k = 0; k < 32; ++k) {
            float w2t = 0.f;
            for (int j = 0; j < 32; ++j) w2t = fmaf(ff_W2[k * 32 + j], ts_W[j], w2t);
            a = fmaf(ff_b1[k], w2t, a);
        }
        cfin_s = a;
    }

    const int t = tid & 31, g = tid >> 5;
    const size_t base = (size_t)blockIdx.x * 32;

    #pragma unroll
    for (int u = 0; u < 2; ++u) {
        const int e = tid + u * 512;
        const int tt = e >> 5, c = e & 31;
        Xs[tt][c] = children[((base + tt) * 16 + 0) * 32 + c];
    }
    __syncthreads();

    for (int it = 1; it <= 16; ++it) {
        const bool fin = (it == 16);
        if (!fin) {
            #pragma unroll
            for (int u = 0; u < 2; ++u) {
                const int e = tid + u * 512;
                const int tt = e >> 5, c = e & 31;
                Xs[tt][32 + c] = children[((base + tt) * 16 + it) * 32 + c];
            }
        } else {
            float sv[2];
            #pragma unroll
            for (int u = 0; u < 2; ++u) {
                const int e = tid + u * 512;
                sv[u] = Xs[e >> 5][e & 31];
            }
            __syncthreads();
            #pragma unroll
            for (int u = 0; u < 2; ++u) {
                const int e = tid + u * 512;
                const int tt = e >> 5, c = e & 31;
                Xs[tt][32 + c] = sv[u];
                Xs[tt][c] = node_tmp[(base + tt) * 32 + c];
            }
        }
        __syncthreads();

        const float* __restrict__ W1c = fin ? W1b : W1a;
        const float* __restrict__ W2c = fin ? W2b : W2a;
        const float* __restrict__ b1c = fin ? b1b : b1a;
        const float* __restrict__ b2c = fin ? b2b : b2a;

        {
            const int c0 = g * 8;
            float h[8];
            #pragma unroll
            for (int j = 0; j < 8; ++j) h[j] = b1c[c0 + j];
            #pragma unroll 4
            for (int k = 0; k < 64; k += 2) {
                const float2 xv = *(const float2*)&Xs[t][k];
                const float4 w00 = *(const float4*)&W1c[k * 128 + c0];
                const float4 w01 = *(const float4*)&W1c[k * 128 + c0 + 4];
                const float4 w10 = *(const float4*)&W1c[(k + 1) * 128 + c0];
                const float4 w11 = *(const float4*)&W1c[(k + 1) * 128 + c0 + 4];
                h[0] = fmaf(xv.x, w00.x, h[0]); h[1] = fmaf(xv.x, w00.y, h[1]);
                h[2] = fmaf(xv.x, w00.z, h[2]); h[3] = fmaf(xv.x, w00.w, h[3]);
                h[4] = fmaf(xv.x, w01.x, h[4]); h[5] = fmaf(xv.x, w01.y, h[5]);
                h[6] = fmaf(xv.x, w01.z, h[6]); h[7] = fmaf(xv.x, w01.w, h[7]);
                h[0] = fmaf(xv.y, w10.x, h[0]); h[1] = fmaf(xv.y, w10.y, h[1]);
                h[2] = fmaf(xv.y, w10.z, h[2]); h[3] = fmaf(xv.y, w10.w, h[3]);
                h[4] = fmaf(xv.y, w11.x, h[4]); h[5] = fmaf(xv.y, w11.y, h[5]);
                h[6] = fmaf(xv.y, w11.z, h[6]); h[7] = fmaf(xv.y, w11.w, h[7]);
            }
            #pragma unroll
            for (int j = 0; j < 8; ++j) Hs[t][c0 + j] = h[j] > 0.f ? h[j] : 0.f;
        }
        __syncthreads();
        {
            const int c2 = g * 2;
            float o0 = b2c[c2], o1 = b2c[c2 + 1];
            #pragma unroll 4
            for (int k = 0; k < 128; k += 2) {
                const float2 hv = *(const float2*)&Hs[t][k];
                const float2 wA = *(const float2*)&W2c[k * 32 + c2];
                const float2 wB = *(const float2*)&W2c[(k + 1) * 32 + c2];
                o0 = fmaf(hv.x, wA.x, o0); o1 = fmaf(hv.x, wA.y, o1);
                o0 = fmaf(hv.y, wB.x, o0); o1 = fmaf(hv.y, wB.y, o1);
            }
            Xs[t][c2]     = o0 > 0.f ? o0 : 0.f;
            Xs[t][c2 + 1] = o1 > 0.f ? o1 : 0.f;
        }
        __syncthreads();
    }

    if (tid < 32) {
        float a = cfin_s;
        #pragma unroll
        for (int c = 0; c < 32; ++c) a = fmaf(Xs[tid][c], vfin[c], a);
        out[base + tid] = a;
    }
}

extern "C" void kernel_launch(void* const* d_in, const int* in_sizes, int n_in,
                              void* d_out, int out_size, void* d_ws, size_t ws_size,
                              hipStream_t stream) {
    const int*   trees      = (const int*)d_in[0];
    const float* lstm       = (const float*)d_in[1];
    const float* embedding  = (const float*)d_in[4];
    const float* leaf_end_W = (const float*)d_in[5];
    const float* leaf_end_b = (const float*)d_in[6];
    const float* lc_W1 = (const float*)d_in[7];
    const float* lc_b1 = (const float*)d_in[8];
    const float* lc_W2 = (const float*)d_in[9];
    const float* lc_b2 = (const float*)d_in[10];
    const float* cs_W1 = (const float*)d_in[11];
    const float* cs_b1 = (const float*)d_in[12];
    const float* cs_W2 = (const float*)d_in[13];
    const float* cs_b2 = (const float*)d_in[14];
    const float* nf_W1 = (const float*)d_in[15];
    const float* nf_b1 = (const float*)d_in[16];
    const float* nf_W2 = (const float*)d_in[17];
    const float* nf_b2 = (const float*)d_in[18];
    const float* cb_W1 = (const float*)d_in[19];
    const float* cb_b1 = (const float*)d_in[20];
    const float* cb_W2 = (const float*)d_in[21];
    const float* cb_b2 = (const float*)d_in[22];
    const float* ff_W1 = (const float*)d_in[23];
    const float* ff_b1 = (const float*)d_in[24];
    const float* ff_W2 = (const float*)d_in[25];
    const float* ff_b2 = (const float*)d_in[26];
    const float* ts_W  = (const float*)d_in[27];
    const float* ts_b  = (const float*)d_in[28];

    char* ws = (char*)d_ws;
    float*  children = (float*)ws;                               // 16 MiB
    float*  node_tmp = (float*)(ws + 16777216);                  // 1 MiB
    __bf16* lcW1T    = (__bf16*)(ws + 17825792);                 // 120 KiB
    __bf16* nfW1T    = (__bf16*)(ws + 17948672);                 // 120 KiB
    __bf16* lcW2T    = (__bf16*)(ws + 18071552);                 // 8 KiB
    __bf16* nfW2T    = (__bf16*)(ws + 18079744);                 // 8 KiB
    __bf16* emb_bf   = (__bf16*)(ws + 18087936);                 // 6.4 KiB
    float*  endvec   = (float*)(ws + 18094592);                  // 128 B
    float*  outp     = (float*)d_out;

    prep_kernel<<<dim3(525), dim3(256), 0, stream>>>(
        embedding, leaf_end_W, leaf_end_b, lc_W1, lc_W2, nf_W1, nf_W2,
        lcW1T, nfW1T, lcW2T, nfW2T, emb_bf, endvec);

    mlp1_mfma<<<dim3(1088), dim3(256), 0, stream>>>(
        trees, lstm, lcW1T, nfW1T, lcW2T, nfW2T, emb_bf, endvec,
        lc_b1, lc_b2, nf_b1, nf_b2, children, node_tmp);

    scan_kernel<<<dim3(256), dim3(512), 0, stream>>>(
        children, node_tmp,
        cs_W1, cs_b1, cs_W2, cs_b2, cb_W1, cb_b1, cb_W2, cb_b2,
        ff_W1, ff_b1, ff_W2, ff_b2, ts_W, ts_b, outp);
}

// Round 3
// 136.420 us; speedup vs baseline: 3.4770x; 1.4665x over previous
//
#include <hip/hip_runtime.h>
#include <cstddef>

// B=8192 trees, 16 leaves + 1 root. FEAT=480 (14 tok x 16 emb + 256 lstm).
// prep_kernel: bf16 transposes of lc/nf W1/W2, bf16 embedding, endvec,
//              hi/lo-split bf16 transposes of cs/cb W1/W2, vfin/cfin collapse.
// mlp1_mfma:   fused gather + MFMA MLP (480->128 relu ->32 relu), 64 rows/block.
// scan_mfma:   64 trees/block, 15 cs steps + cb combine, MFMA with hi/lo split
//              (f32-equivalent accuracy), weights register-resident, fused final dot.

typedef __bf16 bf16x8 __attribute__((ext_vector_type(8)));
typedef float  f32x4  __attribute__((ext_vector_type(4)));

__global__ __launch_bounds__(256) void prep_kernel(
    const float* __restrict__ embedding,
    const float* __restrict__ leaf_end_W, const float* __restrict__ leaf_end_b,
    const float* __restrict__ lc_W1, const float* __restrict__ lc_W2,
    const float* __restrict__ nf_W1, const float* __restrict__ nf_W2,
    const float* __restrict__ cs_W1, const float* __restrict__ cs_W2,
    const float* __restrict__ cb_W1, const float* __restrict__ cb_W2,
    const float* __restrict__ ff_W1, const float* __restrict__ ff_b1,
    const float* __restrict__ ff_W2, const float* __restrict__ ff_b2,
    const float* __restrict__ ts_W, const float* __restrict__ ts_b,
    __bf16* __restrict__ lcW1T, __bf16* __restrict__ nfW1T,
    __bf16* __restrict__ lcW2T, __bf16* __restrict__ nfW2T,
    __bf16* __restrict__ emb_bf, float* __restrict__ endvec,
    __bf16* __restrict__ csW1Th, __bf16* __restrict__ csW1Tl,
    __bf16* __restrict__ cbW1Th, __bf16* __restrict__ cbW1Tl,
    __bf16* __restrict__ csW2Th, __bf16* __restrict__ csW2Tl,
    __bf16* __restrict__ cbW2Th, __bf16* __restrict__ cbW2Tl,
    float* __restrict__ vfin, float* __restrict__ cfin)
{
    const int id = blockIdx.x * 256 + threadIdx.x;
    if (id < 61440) {                        // lcW1T[n][k] = lc_W1[k][n]
        const int n = id / 480, k = id - n * 480;
        lcW1T[id] = (__bf16)lc_W1[k * 128 + n];
    } else if (id < 122880) {
        const int e = id - 61440;
        const int n = e / 480, k = e - n * 480;
        nfW1T[e] = (__bf16)nf_W1[k * 128 + n];
    } else if (id < 126976) {                // lcW2T[n][k] = lc_W2[k][n]
        const int e = id - 122880;
        const int n = e / 128, k = e - n * 128;
        lcW2T[e] = (__bf16)lc_W2[k * 32 + n];
    } else if (id < 131072) {
        const int e = id - 126976;
        const int n = e / 128, k = e - n * 128;
        nfW2T[e] = (__bf16)nf_W2[k * 32 + n];
    } else if (id < 134272) {
        emb_bf[id - 131072] = (__bf16)embedding[id - 131072];
    } else if (id < 134304) {                // endvec = emb[1] @ leaf_end_W + b
        const int c = id - 134272;
        float a = leaf_end_b[c];
        #pragma unroll
        for (int d = 0; d < 16; ++d) a = fmaf(embedding[16 + d], leaf_end_W[d * 32 + c], a);
        endvec[c] = a;
    } else if (id < 142496) {                // csW1T hi/lo [128][64]
        const int e = id - 134304;
        const int n = e >> 6, k = e & 63;
        const float v = cs_W1[k * 128 + n];
        const __bf16 h = (__bf16)v;
        csW1Th[e] = h; csW1Tl[e] = (__bf16)(v - (float)h);
    } else if (id < 150688) {                // cbW1T hi/lo
        const int e = id - 142496;
        const int n = e >> 6, k = e & 63;
        const float v = cb_W1[k * 128 + n];
        const __bf16 h = (__bf16)v;
        cbW1Th[e] = h; cbW1Tl[e] = (__bf16)(v - (float)h);
    } else if (id < 154784) {                // csW2T hi/lo [32][128]
        const int e = id - 150688;
        const int n = e >> 7, k = e & 127;
        const float v = cs_W2[k * 32 + n];
        const __bf16 h = (__bf16)v;
        csW2Th[e] = h; csW2Tl[e] = (__bf16)(v - (float)h);
    } else if (id < 158880) {                // cbW2T hi/lo
        const int e = id - 154784;
        const int n = e >> 7, k = e & 127;
        const float v = cb_W2[k * 32 + n];
        const __bf16 h = (__bf16)v;
        cbW2Th[e] = h; cbW2Tl[e] = (__bf16)(v - (float)h);
    } else if (id < 158912) {                // vfin[c] = ff_W1[c] . (ff_W2 @ ts_W)
        const int c = id - 158880;
        float w2t[32];
        #pragma unroll
        for (int k = 0; k < 32; ++k) {
            float a = 0.f;
            for (int j = 0; j < 32; ++j) a = fmaf(ff_W2[k * 32 + j], ts_W[j], a);
            w2t[k] = a;
        }
        float a = 0.f;
        #pragma unroll
        for (int k = 0; k < 32; ++k) a = fmaf(ff_W1[c * 32 + k], w2t[k], a);
        vfin[c] = a;
    } else if (id == 158912) {
        float a = ts_b[0];
        for (int j = 0; j < 32; ++j) a = fmaf(ff_b2[j], ts_W[j], a);
        for (int k = 0; k < 32; ++k) {
            float w2t = 0.f;
            for (int j = 0; j < 32; ++j) w2t = fmaf(ff_W2[k * 32 + j], ts_W[j], w2t);
            a = fmaf(ff_b1[k], w2t, a);
        }
        cfin[0] = a;
    }
}

// 64 rows per block: leaf blocks 0..2047 (131072 leaf rows), node blocks 2048..2175.
__global__ __launch_bounds__(256) void mlp1_mfma(
    const int* __restrict__ trees,
    const float* __restrict__ lstm,
    const __bf16* __restrict__ lcW1T, const __bf16* __restrict__ nfW1T,
    const __bf16* __restrict__ lcW2T, const __bf16* __restrict__ nfW2T,
    const __bf16* __restrict__ emb_bf, const float* __restrict__ endvec,
    const float* __restrict__ lc_b1, const float* __restrict__ lc_b2,
    const float* __restrict__ nf_b1, const float* __restrict__ nf_b2,
    float* __restrict__ children,
    float* __restrict__ node_tmp)
{
    __shared__ __align__(16) __bf16 emb_s[3200];
    __shared__ __align__(16) __bf16 Hs[64][136];
    __shared__ float b1s[128], b2s[32], evs[32];
    __shared__ int   endf[64];

    const int tid = threadIdx.x;
    const int blk = blockIdx.x;
    const bool leaf = (blk < 2048);

    const __bf16* __restrict__ W1T = leaf ? lcW1T : nfW1T;
    const __bf16* __restrict__ W2T = leaf ? lcW2T : nfW2T;
    const float*  __restrict__ b1p = leaf ? lc_b1 : nf_b1;
    const float*  __restrict__ b2p = leaf ? lc_b2 : nf_b2;

    for (int i = tid; i < 3200; i += 256) emb_s[i] = emb_bf[i];
    if (tid < 128) b1s[tid] = b1p[tid];
    if (tid < 32)  { b2s[tid] = b2p[tid]; evs[tid] = leaf ? endvec[tid] : 0.f; }
    if (tid < 64) {
        if (leaf) {
            const int R = blk * 64 + tid;
            const int b = R >> 4, trow = 1 + (R & 15);
            endf[tid] = (trees[(b * 17 + trow) * 17 + 2] == 1);
        } else endf[tid] = 0;
    }

    const int l  = tid & 63;
    const int w  = tid >> 6;        // wave 0..3
    const int wm = w >> 1;          // row half (32 rows)
    const int wn = w & 1;           // col half (64 cols)
    const int lm = l & 15;
    const int kb = l >> 4;          // k sub-block 0..3

    const int* tb[2];
    const float* lb[2];
    #pragma unroll
    for (int i = 0; i < 2; ++i) {
        const int r = wm * 32 + i * 16 + lm;
        int b, trow;
        if (leaf) { const int R = blk * 64 + r; b = R >> 4; trow = 1 + (R & 15); }
        else      { b = (blk - 2048) * 64 + r; trow = 0; }
        const int* t = trees + (b * 17 + trow) * 17;
        tb[i] = t;
        lb[i] = lstm + ((size_t)b * 64 + (size_t)t[16]) * 256;
    }

    f32x4 acc[2][4];
    #pragma unroll
    for (int i = 0; i < 2; ++i)
        #pragma unroll
        for (int j = 0; j < 4; ++j) acc[i][j] = (f32x4){0.f, 0.f, 0.f, 0.f};

    __syncthreads();

    // layer 1: 480 -> 128 in 15 K-chunks of 32
    #pragma unroll
    for (int c = 0; c < 15; ++c) {
        bf16x8 bfr[4];
        #pragma unroll
        for (int ct = 0; ct < 4; ++ct) {
            const int n = wn * 64 + ct * 16 + lm;
            bfr[ct] = *(const bf16x8*)(W1T + n * 480 + c * 32 + kb * 8);
        }
        bf16x8 afr[2];
        if (c < 7) {
            #pragma unroll
            for (int i = 0; i < 2; ++i) {
                const int tok = tb[i][2 + 2 * c + (kb >> 1)];
                afr[i] = *(const bf16x8*)(emb_s + tok * 16 + (kb & 1) * 8);
            }
        } else {
            #pragma unroll
            for (int i = 0; i < 2; ++i) {
                const float* p = lb[i] + (c - 7) * 32 + kb * 8;
                const float4 u = *(const float4*)p;
                const float4 v = *(const float4*)(p + 4);
                bf16x8 t;
                t[0] = (__bf16)u.x; t[1] = (__bf16)u.y; t[2] = (__bf16)u.z; t[3] = (__bf16)u.w;
                t[4] = (__bf16)v.x; t[5] = (__bf16)v.y; t[6] = (__bf16)v.z; t[7] = (__bf16)v.w;
                afr[i] = t;
            }
        }
        #pragma unroll
        for (int i = 0; i < 2; ++i)
            #pragma unroll
            for (int ct = 0; ct < 4; ++ct)
                acc[i][ct] = __builtin_amdgcn_mfma_f32_16x16x32_bf16(afr[i], bfr[ct], acc[i][ct], 0, 0, 0);
    }

    #pragma unroll
    for (int i = 0; i < 2; ++i)
        #pragma unroll
        for (int ct = 0; ct < 4; ++ct) {
            const int col = wn * 64 + ct * 16 + lm;
            const float bias = b1s[col];
            #pragma unroll
            for (int rg = 0; rg < 4; ++rg) {
                float v = acc[i][ct][rg] + bias;
                v = v > 0.f ? v : 0.f;
                Hs[wm * 32 + i * 16 + 4 * kb + rg][col] = (__bf16)v;
            }
        }
    __syncthreads();

    // layer 2: 64x32, wave w owns M-tile w (rows w*16..+15), both N-tiles
    f32x4 acc2[2];
    acc2[0] = (f32x4){0.f, 0.f, 0.f, 0.f};
    acc2[1] = (f32x4){0.f, 0.f, 0.f, 0.f};

    #pragma unroll
    for (int kc = 0; kc < 4; ++kc) {
        const bf16x8 a2 = *(const bf16x8*)(&Hs[w * 16 + lm][kc * 32 + kb * 8]);
        #pragma unroll
        for (int j = 0; j < 2; ++j) {
            const bf16x8 b2 = *(const bf16x8*)(W2T + (j * 16 + lm) * 128 + kc * 32 + kb * 8);
            acc2[j] = __builtin_amdgcn_mfma_f32_16x16x32_bf16(a2, b2, acc2[j], 0, 0, 0);
        }
    }

    #pragma unroll
    for (int j = 0; j < 2; ++j) {
        const int col = j * 16 + lm;
        const float bias = b2s[col];
        #pragma unroll
        for (int rg = 0; rg < 4; ++rg) {
            const int row = w * 16 + 4 * kb + rg;
            float v = acc2[j][rg] + bias;
            v = v > 0.f ? v : 0.f;
            if (leaf) {
                const size_t R = (size_t)blk * 64 + row;
                children[R * 32 + col] = endf[row] ? evs[col] : v;
            } else {
                const size_t R = (size_t)(blk - 2048) * 64 + row;
                node_tmp[R * 32 + col] = v;
            }
        }
    }
}

// 64 trees per block, 8 waves. X,H in hi/lo bf16 LDS; weights register-resident.
__global__ __launch_bounds__(512) void scan_mfma(
    const float* __restrict__ children,
    const float* __restrict__ node_tmp,
    const __bf16* __restrict__ csW1Th, const __bf16* __restrict__ csW1Tl,
    const __bf16* __restrict__ csW2Th, const __bf16* __restrict__ csW2Tl,
    const __bf16* __restrict__ cbW1Th, const __bf16* __restrict__ cbW1Tl,
    const __bf16* __restrict__ cbW2Th, const __bf16* __restrict__ cbW2Tl,
    const float* __restrict__ cs_b1, const float* __restrict__ cs_b2,
    const float* __restrict__ cb_b1, const float* __restrict__ cb_b2,
    const float* __restrict__ vfin_g, const float* __restrict__ cfin_g,
    float* __restrict__ out)
{
    __shared__ __align__(16) __bf16 Xh[64][72], Xl[64][72];       // stride 144B -> 2-way max
    __shared__ __align__(16) __bf16 Hh[64][136], Hl[64][136];     // stride 272B -> 2-way max
    __shared__ float b1a[128], b1b[128], b2a[32], b2b[32], vfin[32];
    __shared__ float psum[2][64];
    __shared__ float cfin_s;

    const int tid = threadIdx.x;
    const int l = tid & 63, w = tid >> 6;      // 8 waves
    const int lm = l & 15, kb = l >> 4;

    if (tid < 128)      { b1a[tid] = cs_b1[tid]; b1b[tid] = cb_b1[tid]; }
    else if (tid < 160) { b2a[tid - 128] = cs_b2[tid - 128]; b2b[tid - 128] = cb_b2[tid - 128]; }
    else if (tid < 192) { vfin[tid - 160] = vfin_g[tid - 160]; }
    else if (tid == 192) cfin_s = cfin_g[0];

    // persistent cs weights in registers
    // layer1: wave w owns N columns [ (w&3)*32, +32 ): 2 N-tiles x 2 K-chunks
    bf16x8 W1r[2][2][2];   // [nt][kc][hi/lo]
    {
        const int q = w & 3;
        #pragma unroll
        for (int nt = 0; nt < 2; ++nt)
            #pragma unroll
            for (int kc = 0; kc < 2; ++kc) {
                const int n = q * 32 + nt * 16 + lm;
                W1r[nt][kc][0] = *(const bf16x8*)(csW1Th + n * 64 + kc * 32 + kb * 8);
                W1r[nt][kc][1] = *(const bf16x8*)(csW1Tl + n * 64 + kc * 32 + kb * 8);
            }
    }
    // layer2: wave w owns (Mt = w>>1, Nt = w&1); 4 K-chunks
    bf16x8 W2r[4][2];
    {
        const int n2 = (w & 1) * 16 + lm;
        #pragma unroll
        for (int kc = 0; kc < 4; ++kc) {
            W2r[kc][0] = *(const bf16x8*)(csW2Th + n2 * 128 + kc * 32 + kb * 8);
            W2r[kc][1] = *(const bf16x8*)(csW2Tl + n2 * 128 + kc * 32 + kb * 8);
        }
    }

    const size_t base = (size_t)blockIdx.x * 64;
    const int tt = tid >> 3, c4 = (tid & 7) * 4;    // staging role: tree tt, cols c4..c4+3

    // init: carry = children[:,0,:], child = children[:,1,:]
    {
        const float4 v0 = *(const float4*)&children[((base + tt) * 16 + 0) * 32 + c4];
        const float4 v1 = *(const float4*)&children[((base + tt) * 16 + 1) * 32 + c4];
        const float a0[4] = {v0.x, v0.y, v0.z, v0.w};
        const float a1[4] = {v1.x, v1.y, v1.z, v1.w};
        union { __bf16 b[4]; short4 s; } h0, l0, h1, l1;
        #pragma unroll
        for (int j = 0; j < 4; ++j) {
            h0.b[j] = (__bf16)a0[j]; l0.b[j] = (__bf16)(a0[j] - (float)h0.b[j]);
            h1.b[j] = (__bf16)a1[j]; l1.b[j] = (__bf16)(a1[j] - (float)h1.b[j]);
        }
        *(short4*)&Xh[tt][c4]      = h0.s;
        *(short4*)&Xl[tt][c4]      = l0.s;
        *(short4*)&Xh[tt][32 + c4] = h1.s;
        *(short4*)&Xl[tt][32 + c4] = l1.s;
    }
    __syncthreads();

    #pragma unroll 1
    for (int it = 1; it <= 16; ++it) {
        const bool fin = (it == 16);
        if (fin) {   // swap to cb weights (last iteration: safe to overwrite)
            const int q = w & 3;
            #pragma unroll
            for (int nt = 0; nt < 2; ++nt)
                #pragma unroll
                for (int kc = 0; kc < 2; ++kc) {
                    const int n = q * 32 + nt * 16 + lm;
                    W1r[nt][kc][0] = *(const bf16x8*)(cbW1Th + n * 64 + kc * 32 + kb * 8);
                    W1r[nt][kc][1] = *(const bf16x8*)(cbW1Tl + n * 64 + kc * 32 + kb * 8);
                }
            const int n2 = (w & 1) * 16 + lm;
            #pragma unroll
            for (int kc = 0; kc < 4; ++kc) {
                W2r[kc][0] = *(const bf16x8*)(cbW2Th + n2 * 128 + kc * 32 + kb * 8);
                W2r[kc][1] = *(const bf16x8*)(cbW2Tl + n2 * 128 + kc * 32 + kb * 8);
            }
        }
        const float* __restrict__ b1c = fin ? b1b : b1a;
        const float* __restrict__ b2c = fin ? b2b : b2a;

        // prefetch next-step child (or node_tmp before the combine step)
        float4 pf;
        const int pfmode = (it < 15) ? 1 : (it == 15 ? 2 : 0);
        if (pfmode == 1)      pf = *(const float4*)&children[((base + tt) * 16 + (it + 1)) * 32 + c4];
        else if (pfmode == 2) pf = *(const float4*)&node_tmp[(base + tt) * 32 + c4];

        // ---- layer 1: X[64][64] @ W1[64][128] ----
        const int mh = w >> 2, q = w & 3;
        bf16x8 xh[2][2], xl[2][2];
        #pragma unroll
        for (int i = 0; i < 2; ++i)
            #pragma unroll
            for (int kc = 0; kc < 2; ++kc) {
                const int row = mh * 32 + i * 16 + lm;
                xh[i][kc] = *(const bf16x8*)&Xh[row][kc * 32 + kb * 8];
                xl[i][kc] = *(const bf16x8*)&Xl[row][kc * 32 + kb * 8];
            }
        f32x4 a1[2][2];
        #pragma unroll
        for (int i = 0; i < 2; ++i)
            #pragma unroll
            for (int nt = 0; nt < 2; ++nt) {
                a1[i][nt] = (f32x4){0.f, 0.f, 0.f, 0.f};
                #pragma unroll
                for (int kc = 0; kc < 2; ++kc) {
                    a1[i][nt] = __builtin_amdgcn_mfma_f32_16x16x32_bf16(xh[i][kc], W1r[nt][kc][0], a1[i][nt], 0, 0, 0);
                    a1[i][nt] = __builtin_amdgcn_mfma_f32_16x16x32_bf16(xl[i][kc], W1r[nt][kc][0], a1[i][nt], 0, 0, 0);
                    a1[i][nt] = __builtin_amdgcn_mfma_f32_16x16x32_bf16(xh[i][kc], W1r[nt][kc][1], a1[i][nt], 0, 0, 0);
                }
            }
        #pragma unroll
        for (int i = 0; i < 2; ++i)
            #pragma unroll
            for (int nt = 0; nt < 2; ++nt) {
                const int col = q * 32 + nt * 16 + lm;
                const float bias = b1c[col];
                #pragma unroll
                for (int rg = 0; rg < 4; ++rg) {
                    const int row = mh * 32 + i * 16 + 4 * kb + rg;
                    float v = a1[i][nt][rg] + bias;
                    v = v > 0.f ? v : 0.f;
                    const __bf16 h = (__bf16)v;
                    Hh[row][col] = h;
                    Hl[row][col] = (__bf16)(v - (float)h);
                }
            }
        __syncthreads();

        // ---- layer 2: H[64][128] @ W2[128][32] ----
        const int mt = w >> 1;
        f32x4 a2 = (f32x4){0.f, 0.f, 0.f, 0.f};
        #pragma unroll
        for (int kc = 0; kc < 4; ++kc) {
            const bf16x8 ah = *(const bf16x8*)&Hh[mt * 16 + lm][kc * 32 + kb * 8];
            const bf16x8 al = *(const bf16x8*)&Hl[mt * 16 + lm][kc * 32 + kb * 8];
            a2 = __builtin_amdgcn_mfma_f32_16x16x32_bf16(ah, W2r[kc][0], a2, 0, 0, 0);
            a2 = __builtin_amdgcn_mfma_f32_16x16x32_bf16(al, W2r[kc][0], a2, 0, 0, 0);
            a2 = __builtin_amdgcn_mfma_f32_16x16x32_bf16(ah, W2r[kc][1], a2, 0, 0, 0);
        }

        if (!fin) {
            // write new carry (cols 0-31 normally; 32-63 before combine, since
            // combine input is [node_tmp | summary])
            const int cb_ = (it == 15) ? 32 : 0;
            const int col = (w & 1) * 16 + lm;
            const float bias = b2c[col];
            #pragma unroll
            for (int rg = 0; rg < 4; ++rg) {
                const int row = mt * 16 + 4 * kb + rg;
                float v = a2[rg] + bias;
                v = v > 0.f ? v : 0.f;
                const __bf16 h = (__bf16)v;
                Xh[row][cb_ + col] = h;
                Xl[row][cb_ + col] = (__bf16)(v - (float)h);
            }
            if (pfmode) {
                const int dst = (pfmode == 2) ? 0 : 32;
                const float a0[4] = {pf.x, pf.y, pf.z, pf.w};
                union { __bf16 b[4]; short4 s; } hh, ll;
                #pragma unroll
                for (int j = 0; j < 4; ++j) {
                    hh.b[j] = (__bf16)a0[j]; ll.b[j] = (__bf16)(a0[j] - (float)hh.b[j]);
                }
                *(short4*)&Xh[tt][dst + c4] = hh.s;
                *(short4*)&Xl[tt][dst + c4] = ll.s;
            }
            __syncthreads();
        } else {
            // fused final linear: out = tree_sum . vfin + cfin
            const int col = (w & 1) * 16 + lm;
            const float bias = b2c[col];
            const float vf = vfin[col];
            float part[4];
            #pragma unroll
            for (int rg = 0; rg < 4; ++rg) {
                float v = a2[rg] + bias;
                v = v > 0.f ? v : 0.f;
                part[rg] = v * vf;
            }
            #pragma unroll
            for (int m = 1; m < 16; m <<= 1)
                #pragma unroll
                for (int rg = 0; rg < 4; ++rg)
                    part[rg] += __shfl_xor(part[rg], m, 64);
            if (lm == 0) {
                #pragma unroll
                for (int rg = 0; rg < 4; ++rg)
                    psum[w & 1][mt * 16 + 4 * kb + rg] = part[rg];
            }
            __syncthreads();
            if (tid < 64) out[base + tid] = cfin_s + psum[0][tid] + psum[1][tid];
        }
    }
}

extern "C" void kernel_launch(void* const* d_in, const int* in_sizes, int n_in,
                              void* d_out, int out_size, void* d_ws, size_t ws_size,
                              hipStream_t stream) {
    const int*   trees      = (const int*)d_in[0];
    const float* lstm       = (const float*)d_in[1];
    const float* embedding  = (const float*)d_in[4];
    const float* leaf_end_W = (const float*)d_in[5];
    const float* leaf_end_b = (const float*)d_in[6];
    const float* lc_W1 = (const float*)d_in[7];
    const float* lc_b1 = (const float*)d_in[8];
    const float* lc_W2 = (const float*)d_in[9];
    const float* lc_b2 = (const float*)d_in[10];
    const float* cs_W1 = (const float*)d_in[11];
    const float* cs_b1 = (const float*)d_in[12];
    const float* cs_W2 = (const float*)d_in[13];
    const float* cs_b2 = (const float*)d_in[14];
    const float* nf_W1 = (const float*)d_in[15];
    const float* nf_b1 = (const float*)d_in[16];
    const float* nf_W2 = (const float*)d_in[17];
    const float* nf_b2 = (const float*)d_in[18];
    const float* cb_W1 = (const float*)d_in[19];
    const float* cb_b1 = (const float*)d_in[20];
    const float* cb_W2 = (const float*)d_in[21];
    const float* cb_b2 = (const float*)d_in[22];
    const float* ff_W1 = (const float*)d_in[23];
    const float* ff_b1 = (const float*)d_in[24];
    const float* ff_W2 = (const float*)d_in[25];
    const float* ff_b2 = (const float*)d_in[26];
    const float* ts_W  = (const float*)d_in[27];
    const float* ts_b  = (const float*)d_in[28];

    char* ws = (char*)d_ws;
    float*  children = (float*)ws;                               // 16 MiB
    float*  node_tmp = (float*)(ws + 16777216);                  // 1 MiB
    __bf16* lcW1T    = (__bf16*)(ws + 17825792);
    __bf16* nfW1T    = (__bf16*)(ws + 17948672);
    __bf16* lcW2T    = (__bf16*)(ws + 18071552);
    __bf16* nfW2T    = (__bf16*)(ws + 18079744);
    __bf16* emb_bf   = (__bf16*)(ws + 18087936);
    float*  endvec   = (float*)(ws + 18094336);
    __bf16* csW1Th   = (__bf16*)(ws + 18094464);
    __bf16* csW1Tl   = (__bf16*)(ws + 18110848);
    __bf16* cbW1Th   = (__bf16*)(ws + 18127232);
    __bf16* cbW1Tl   = (__bf16*)(ws + 18143616);
    __bf16* csW2Th   = (__bf16*)(ws + 18160000);
    __bf16* csW2Tl   = (__bf16*)(ws + 18168192);
    __bf16* cbW2Th   = (__bf16*)(ws + 18176384);
    __bf16* cbW2Tl   = (__bf16*)(ws + 18184576);
    float*  vfin     = (float*)(ws + 18192768);
    float*  cfin     = (float*)(ws + 18192896);
    float*  outp     = (float*)d_out;

    prep_kernel<<<dim3(621), dim3(256), 0, stream>>>(
        embedding, leaf_end_W, leaf_end_b, lc_W1, lc_W2, nf_W1, nf_W2,
        cs_W1, cs_W2, cb_W1, cb_W2, ff_W1, ff_b1, ff_W2, ff_b2, ts_W, ts_b,
        lcW1T, nfW1T, lcW2T, nfW2T, emb_bf, endvec,
        csW1Th, csW1Tl, cbW1Th, cbW1Tl, csW2Th, csW2Tl, cbW2Th, cbW2Tl,
        vfin, cfin);

    mlp1_mfma<<<dim3(2176), dim3(256), 0, stream>>>(
        trees, lstm, lcW1T, nfW1T, lcW2T, nfW2T, emb_bf, endvec,
        lc_b1, lc_b2, nf_b1, nf_b2, children, node_tmp);

    scan_mfma<<<dim3(128), dim3(512), 0, stream>>>(
        children, node_tmp,
        csW1Th, csW1Tl, csW2Th, csW2Tl, cbW1Th, cbW1Tl, cbW2Th, cbW2Tl,
        cs_b1, cs_b2, cb_b1, cb_b2, vfin, cfin, outp);
}

// Round 4
// 129.309 us; speedup vs baseline: 3.6682x; 1.0550x over previous
//
#include <hip/hip_runtime.h>
#include <cstddef>

// B=8192 trees, 16 leaves + 1 root. FEAT=480 (14 tok x 16 emb + 256 lstm).
// prep_kernel: bf16 transposes of lc/nf W1/W2, bf16 embedding, endvec,
//              hi/lo-split bf16 transposes of cs/cb W1/W2, vfin/cfin collapse.
// mlp1_mfma:   fused gather + MFMA MLP (480->128 relu ->32 relu), 64 rows/block,
//              outputs stored as bf16 hi/lo SoA (conversion at producer).
// scan_mfma:   32 trees/block x 256 blocks (full GPU), 15 cs steps + cb combine,
//              MFMA hi/lo split, weights register-resident, fused final dot.

typedef __bf16 bf16x8 __attribute__((ext_vector_type(8)));
typedef __bf16 bf16x4 __attribute__((ext_vector_type(4)));
typedef float  f32x4  __attribute__((ext_vector_type(4)));

__global__ __launch_bounds__(256) void prep_kernel(
    const float* __restrict__ embedding,
    const float* __restrict__ leaf_end_W, const float* __restrict__ leaf_end_b,
    const float* __restrict__ lc_W1, const float* __restrict__ lc_W2,
    const float* __restrict__ nf_W1, const float* __restrict__ nf_W2,
    const float* __restrict__ cs_W1, const float* __restrict__ cs_W2,
    const float* __restrict__ cb_W1, const float* __restrict__ cb_W2,
    const float* __restrict__ ff_W1, const float* __restrict__ ff_b1,
    const float* __restrict__ ff_W2, const float* __restrict__ ff_b2,
    const float* __restrict__ ts_W, const float* __restrict__ ts_b,
    __bf16* __restrict__ lcW1T, __bf16* __restrict__ nfW1T,
    __bf16* __restrict__ lcW2T, __bf16* __restrict__ nfW2T,
    __bf16* __restrict__ emb_bf, float* __restrict__ endvec,
    __bf16* __restrict__ csW1Th, __bf16* __restrict__ csW1Tl,
    __bf16* __restrict__ cbW1Th, __bf16* __restrict__ cbW1Tl,
    __bf16* __restrict__ csW2Th, __bf16* __restrict__ csW2Tl,
    __bf16* __restrict__ cbW2Th, __bf16* __restrict__ cbW2Tl,
    float* __restrict__ vfin, float* __restrict__ cfin)
{
    const int id = blockIdx.x * 256 + threadIdx.x;
    if (id < 61440) {                        // lcW1T[n][k] = lc_W1[k][n]
        const int n = id / 480, k = id - n * 480;
        lcW1T[id] = (__bf16)lc_W1[k * 128 + n];
    } else if (id < 122880) {
        const int e = id - 61440;
        const int n = e / 480, k = e - n * 480;
        nfW1T[e] = (__bf16)nf_W1[k * 128 + n];
    } else if (id < 126976) {                // lcW2T[n][k] = lc_W2[k][n]
        const int e = id - 122880;
        const int n = e / 128, k = e - n * 128;
        lcW2T[e] = (__bf16)lc_W2[k * 32 + n];
    } else if (id < 131072) {
        const int e = id - 126976;
        const int n = e / 128, k = e - n * 128;
        nfW2T[e] = (__bf16)nf_W2[k * 32 + n];
    } else if (id < 134272) {
        emb_bf[id - 131072] = (__bf16)embedding[id - 131072];
    } else if (id < 134304) {                // endvec = emb[1] @ leaf_end_W + b
        const int c = id - 134272;
        float a = leaf_end_b[c];
        #pragma unroll
        for (int d = 0; d < 16; ++d) a = fmaf(embedding[16 + d], leaf_end_W[d * 32 + c], a);
        endvec[c] = a;
    } else if (id < 142496) {                // csW1T hi/lo [128][64]
        const int e = id - 134304;
        const int n = e >> 6, k = e & 63;
        const float v = cs_W1[k * 128 + n];
        const __bf16 h = (__bf16)v;
        csW1Th[e] = h; csW1Tl[e] = (__bf16)(v - (float)h);
    } else if (id < 150688) {                // cbW1T hi/lo
        const int e = id - 142496;
        const int n = e >> 6, k = e & 63;
        const float v = cb_W1[k * 128 + n];
        const __bf16 h = (__bf16)v;
        cbW1Th[e] = h; cbW1Tl[e] = (__bf16)(v - (float)h);
    } else if (id < 154784) {                // csW2T hi/lo [32][128]
        const int e = id - 150688;
        const int n = e >> 7, k = e & 127;
        const float v = cs_W2[k * 32 + n];
        const __bf16 h = (__bf16)v;
        csW2Th[e] = h; csW2Tl[e] = (__bf16)(v - (float)h);
    } else if (id < 158880) {                // cbW2T hi/lo
        const int e = id - 154784;
        const int n = e >> 7, k = e & 127;
        const float v = cb_W2[k * 32 + n];
        const __bf16 h = (__bf16)v;
        cbW2Th[e] = h; cbW2Tl[e] = (__bf16)(v - (float)h);
    } else if (id < 158912) {                // vfin[c] = ff_W1[c] . (ff_W2 @ ts_W)
        const int c = id - 158880;
        float w2t[32];
        #pragma unroll
        for (int k = 0; k < 32; ++k) {
            float a = 0.f;
            for (int j = 0; j < 32; ++j) a = fmaf(ff_W2[k * 32 + j], ts_W[j], a);
            w2t[k] = a;
        }
        float a = 0.f;
        #pragma unroll
        for (int k = 0; k < 32; ++k) a = fmaf(ff_W1[c * 32 + k], w2t[k], a);
        vfin[c] = a;
    } else if (id == 158912) {
        float a = ts_b[0];
        for (int j = 0; j < 32; ++j) a = fmaf(ff_b2[j], ts_W[j], a);
        for (int k = 0; k < 32; ++k) {
            float w2t = 0.f;
            for (int j = 0; j < 32; ++j) w2t = fmaf(ff_W2[k * 32 + j], ts_W[j], w2t);
            a = fmaf(ff_b1[k], w2t, a);
        }
        cfin[0] = a;
    }
}

// 64 rows per block: leaf blocks 0..2047 (131072 leaf rows), node blocks 2048..2175.
__global__ __launch_bounds__(256, 4) void mlp1_mfma(
    const int* __restrict__ trees,
    const float* __restrict__ lstm,
    const __bf16* __restrict__ lcW1T, const __bf16* __restrict__ nfW1T,
    const __bf16* __restrict__ lcW2T, const __bf16* __restrict__ nfW2T,
    const __bf16* __restrict__ emb_bf, const float* __restrict__ endvec,
    const float* __restrict__ lc_b1, const float* __restrict__ lc_b2,
    const float* __restrict__ nf_b1, const float* __restrict__ nf_b2,
    __bf16* __restrict__ childrenH, __bf16* __restrict__ childrenL,
    __bf16* __restrict__ node_tmpH, __bf16* __restrict__ node_tmpL)
{
    __shared__ __align__(16) __bf16 emb_s[3200];
    __shared__ __align__(16) __bf16 Hs[64][136];
    __shared__ float b1s[128], b2s[32], evs[32];
    __shared__ int   endf[64];

    const int tid = threadIdx.x;
    const int blk = blockIdx.x;
    const bool leaf = (blk < 2048);

    const __bf16* __restrict__ W1T = leaf ? lcW1T : nfW1T;
    const __bf16* __restrict__ W2T = leaf ? lcW2T : nfW2T;
    const float*  __restrict__ b1p = leaf ? lc_b1 : nf_b1;
    const float*  __restrict__ b2p = leaf ? lc_b2 : nf_b2;

    for (int i = tid; i < 3200; i += 256) emb_s[i] = emb_bf[i];
    if (tid < 128) b1s[tid] = b1p[tid];
    if (tid < 32)  { b2s[tid] = b2p[tid]; evs[tid] = leaf ? endvec[tid] : 0.f; }
    if (tid < 64) {
        if (leaf) {
            const int R = blk * 64 + tid;
            const int b = R >> 4, trow = 1 + (R & 15);
            endf[tid] = (trees[(b * 17 + trow) * 17 + 2] == 1);
        } else endf[tid] = 0;
    }

    const int l  = tid & 63;
    const int w  = tid >> 6;        // wave 0..3
    const int wm = w >> 1;          // row half (32 rows)
    const int wn = w & 1;           // col half (64 cols)
    const int lm = l & 15;
    const int kb = l >> 4;          // k sub-block 0..3

    const int* tb[2];
    const float* lb[2];
    #pragma unroll
    for (int i = 0; i < 2; ++i) {
        const int r = wm * 32 + i * 16 + lm;
        int b, trow;
        if (leaf) { const int R = blk * 64 + r; b = R >> 4; trow = 1 + (R & 15); }
        else      { b = (blk - 2048) * 64 + r; trow = 0; }
        const int* t = trees + (b * 17 + trow) * 17;
        tb[i] = t;
        lb[i] = lstm + ((size_t)b * 64 + (size_t)t[16]) * 256;
    }

    f32x4 acc[2][4];
    #pragma unroll
    for (int i = 0; i < 2; ++i)
        #pragma unroll
        for (int j = 0; j < 4; ++j) acc[i][j] = (f32x4){0.f, 0.f, 0.f, 0.f};

    __syncthreads();

    // layer 1: 480 -> 128 in 15 K-chunks of 32
    #pragma unroll
    for (int c = 0; c < 15; ++c) {
        bf16x8 bfr[4];
        #pragma unroll
        for (int ct = 0; ct < 4; ++ct) {
            const int n = wn * 64 + ct * 16 + lm;
            bfr[ct] = *(const bf16x8*)(W1T + n * 480 + c * 32 + kb * 8);
        }
        bf16x8 afr[2];
        if (c < 7) {
            #pragma unroll
            for (int i = 0; i < 2; ++i) {
                const int tok = tb[i][2 + 2 * c + (kb >> 1)];
                afr[i] = *(const bf16x8*)(emb_s + tok * 16 + (kb & 1) * 8);
            }
        } else {
            #pragma unroll
            for (int i = 0; i < 2; ++i) {
                const float* p = lb[i] + (c - 7) * 32 + kb * 8;
                const float4 u = *(const float4*)p;
                const float4 v = *(const float4*)(p + 4);
                bf16x8 t;
                t[0] = (__bf16)u.x; t[1] = (__bf16)u.y; t[2] = (__bf16)u.z; t[3] = (__bf16)u.w;
                t[4] = (__bf16)v.x; t[5] = (__bf16)v.y; t[6] = (__bf16)v.z; t[7] = (__bf16)v.w;
                afr[i] = t;
            }
        }
        #pragma unroll
        for (int i = 0; i < 2; ++i)
            #pragma unroll
            for (int ct = 0; ct < 4; ++ct)
                acc[i][ct] = __builtin_amdgcn_mfma_f32_16x16x32_bf16(afr[i], bfr[ct], acc[i][ct], 0, 0, 0);
    }

    #pragma unroll
    for (int i = 0; i < 2; ++i)
        #pragma unroll
        for (int ct = 0; ct < 4; ++ct) {
            const int col = wn * 64 + ct * 16 + lm;
            const float bias = b1s[col];
            #pragma unroll
            for (int rg = 0; rg < 4; ++rg) {
                float v = acc[i][ct][rg] + bias;
                v = v > 0.f ? v : 0.f;
                Hs[wm * 32 + i * 16 + 4 * kb + rg][col] = (__bf16)v;
            }
        }
    __syncthreads();

    // layer 2: 64x32, wave w owns M-tile w (rows w*16..+15), both N-tiles
    f32x4 acc2[2];
    acc2[0] = (f32x4){0.f, 0.f, 0.f, 0.f};
    acc2[1] = (f32x4){0.f, 0.f, 0.f, 0.f};

    #pragma unroll
    for (int kc = 0; kc < 4; ++kc) {
        const bf16x8 a2 = *(const bf16x8*)(&Hs[w * 16 + lm][kc * 32 + kb * 8]);
        #pragma unroll
        for (int j = 0; j < 2; ++j) {
            const bf16x8 b2 = *(const bf16x8*)(W2T + (j * 16 + lm) * 128 + kc * 32 + kb * 8);
            acc2[j] = __builtin_amdgcn_mfma_f32_16x16x32_bf16(a2, b2, acc2[j], 0, 0, 0);
        }
    }

    #pragma unroll
    for (int j = 0; j < 2; ++j) {
        const int col = j * 16 + lm;
        const float bias = b2s[col];
        #pragma unroll
        for (int rg = 0; rg < 4; ++rg) {
            const int row = w * 16 + 4 * kb + rg;
            float v = acc2[j][rg] + bias;
            v = v > 0.f ? v : 0.f;
            if (leaf && endf[row]) v = evs[col];
            const __bf16 h  = (__bf16)v;
            const __bf16 lo = (__bf16)(v - (float)h);
            if (leaf) {
                const size_t R = (size_t)blk * 64 + row;
                childrenH[R * 32 + col] = h;
                childrenL[R * 32 + col] = lo;
            } else {
                const size_t R = (size_t)(blk - 2048) * 64 + row;
                node_tmpH[R * 32 + col] = h;
                node_tmpL[R * 32 + col] = lo;
            }
        }
    }
}

// 32 trees per block, 256 blocks, 4 waves. X,H hi/lo bf16 LDS; weights in regs.
__global__ __launch_bounds__(256) void scan_mfma(
    const __bf16* __restrict__ childrenH, const __bf16* __restrict__ childrenL,
    const __bf16* __restrict__ node_tmpH, const __bf16* __restrict__ node_tmpL,
    const __bf16* __restrict__ csW1Th, const __bf16* __restrict__ csW1Tl,
    const __bf16* __restrict__ csW2Th, const __bf16* __restrict__ csW2Tl,
    const __bf16* __restrict__ cbW1Th, const __bf16* __restrict__ cbW1Tl,
    const __bf16* __restrict__ cbW2Th, const __bf16* __restrict__ cbW2Tl,
    const float* __restrict__ cs_b1, const float* __restrict__ cs_b2,
    const float* __restrict__ cb_b1, const float* __restrict__ cb_b2,
    const float* __restrict__ vfin_g, const float* __restrict__ cfin_g,
    float* __restrict__ out)
{
    __shared__ __align__(16) __bf16 Xh[32][72], Xl[32][72];       // stride 144B
    __shared__ __align__(16) __bf16 Hh[32][136], Hl[32][136];     // stride 272B
    __shared__ float b1a[128], b1b[128], b2a[32], b2b[32], vfin[32];
    __shared__ float psum[2][32];
    __shared__ float cfin_s;

    const int tid = threadIdx.x;
    const int l = tid & 63, w = tid >> 6;      // 4 waves
    const int lm = l & 15, kb = l >> 4;

    if (tid < 128)      { b1a[tid] = cs_b1[tid]; b1b[tid] = cb_b1[tid]; }
    else if (tid < 160) { b2a[tid - 128] = cs_b2[tid - 128]; b2b[tid - 128] = cb_b2[tid - 128]; }
    else if (tid < 192) { vfin[tid - 160] = vfin_g[tid - 160]; }
    else if (tid == 192) cfin_s = cfin_g[0];

    // persistent cs weights in registers
    // layer1: wave w owns N cols [w*32, +32): 2 N-tiles x 2 K-chunks
    bf16x8 W1r[2][2][2];   // [nt][kc][hi/lo]
    {
        #pragma unroll
        for (int nt = 0; nt < 2; ++nt)
            #pragma unroll
            for (int kc = 0; kc < 2; ++kc) {
                const int n = w * 32 + nt * 16 + lm;
                W1r[nt][kc][0] = *(const bf16x8*)(csW1Th + n * 64 + kc * 32 + kb * 8);
                W1r[nt][kc][1] = *(const bf16x8*)(csW1Tl + n * 64 + kc * 32 + kb * 8);
            }
    }
    // layer2: wave w owns (mt = w>>1, n2 = w&1); 4 K-chunks
    bf16x8 W2r[4][2];
    {
        const int n2 = (w & 1) * 16 + lm;
        #pragma unroll
        for (int kc = 0; kc < 4; ++kc) {
            W2r[kc][0] = *(const bf16x8*)(csW2Th + n2 * 128 + kc * 32 + kb * 8);
            W2r[kc][1] = *(const bf16x8*)(csW2Tl + n2 * 128 + kc * 32 + kb * 8);
        }
    }

    const size_t base = (size_t)blockIdx.x * 32;
    const int tt = tid >> 3, c4 = (tid & 7) * 4;    // staging: tree tt, cols c4..c4+3

    // init: carry = children[:,0,:], child = children[:,1,:] (bf16 hi/lo direct)
    {
        const size_t o0 = ((base + tt) * 16 + 0) * 32 + c4;
        const size_t o1 = ((base + tt) * 16 + 1) * 32 + c4;
        *(bf16x4*)&Xh[tt][c4]      = *(const bf16x4*)(childrenH + o0);
        *(bf16x4*)&Xl[tt][c4]      = *(const bf16x4*)(childrenL + o0);
        *(bf16x4*)&Xh[tt][32 + c4] = *(const bf16x4*)(childrenH + o1);
        *(bf16x4*)&Xl[tt][32 + c4] = *(const bf16x4*)(childrenL + o1);
    }
    __syncthreads();

    #pragma unroll 1
    for (int it = 1; it <= 16; ++it) {
        const bool fin = (it == 16);
        if (fin) {   // swap to cb weights (last iteration: safe to overwrite)
            #pragma unroll
            for (int nt = 0; nt < 2; ++nt)
                #pragma unroll
                for (int kc = 0; kc < 2; ++kc) {
                    const int n = w * 32 + nt * 16 + lm;
                    W1r[nt][kc][0] = *(const bf16x8*)(cbW1Th + n * 64 + kc * 32 + kb * 8);
                    W1r[nt][kc][1] = *(const bf16x8*)(cbW1Tl + n * 64 + kc * 32 + kb * 8);
                }
            const int n2 = (w & 1) * 16 + lm;
            #pragma unroll
            for (int kc = 0; kc < 4; ++kc) {
                W2r[kc][0] = *(const bf16x8*)(cbW2Th + n2 * 128 + kc * 32 + kb * 8);
                W2r[kc][1] = *(const bf16x8*)(cbW2Tl + n2 * 128 + kc * 32 + kb * 8);
            }
        }
        const float* __restrict__ b1c = fin ? b1b : b1a;
        const float* __restrict__ b2c = fin ? b2b : b2a;

        // prefetch next child (or node_tmp before the combine step)
        bf16x4 pfh, pfl;
        const int pfmode = (it < 15) ? 1 : (it == 15 ? 2 : 0);
        if (pfmode == 1) {
            const size_t o = ((base + tt) * 16 + (it + 1)) * 32 + c4;
            pfh = *(const bf16x4*)(childrenH + o);
            pfl = *(const bf16x4*)(childrenL + o);
        } else if (pfmode == 2) {
            const size_t o = (base + tt) * 32 + c4;
            pfh = *(const bf16x4*)(node_tmpH + o);
            pfl = *(const bf16x4*)(node_tmpL + o);
        }

        // ---- layer 1: X[32][64] @ W1[64][128] ----
        bf16x8 xh[2][2], xl[2][2];
        #pragma unroll
        for (int i = 0; i < 2; ++i)
            #pragma unroll
            for (int kc = 0; kc < 2; ++kc) {
                const int row = i * 16 + lm;
                xh[i][kc] = *(const bf16x8*)&Xh[row][kc * 32 + kb * 8];
                xl[i][kc] = *(const bf16x8*)&Xl[row][kc * 32 + kb * 8];
            }
        f32x4 a1[2][2];
        #pragma unroll
        for (int i = 0; i < 2; ++i)
            #pragma unroll
            for (int nt = 0; nt < 2; ++nt) {
                a1[i][nt] = (f32x4){0.f, 0.f, 0.f, 0.f};
                #pragma unroll
                for (int kc = 0; kc < 2; ++kc) {
                    a1[i][nt] = __builtin_amdgcn_mfma_f32_16x16x32_bf16(xh[i][kc], W1r[nt][kc][0], a1[i][nt], 0, 0, 0);
                    a1[i][nt] = __builtin_amdgcn_mfma_f32_16x16x32_bf16(xl[i][kc], W1r[nt][kc][0], a1[i][nt], 0, 0, 0);
                    a1[i][nt] = __builtin_amdgcn_mfma_f32_16x16x32_bf16(xh[i][kc], W1r[nt][kc][1], a1[i][nt], 0, 0, 0);
                }
            }
        #pragma unroll
        for (int i = 0; i < 2; ++i)
            #pragma unroll
            for (int nt = 0; nt < 2; ++nt) {
                const int col = w * 32 + nt * 16 + lm;
                const float bias = b1c[col];
                #pragma unroll
                for (int rg = 0; rg < 4; ++rg) {
                    const int row = i * 16 + 4 * kb + rg;
                    float v = a1[i][nt][rg] + bias;
                    v = v > 0.f ? v : 0.f;
                    const __bf16 h = (__bf16)v;
                    Hh[row][col] = h;
                    Hl[row][col] = (__bf16)(v - (float)h);
                }
            }
        __syncthreads();

        // ---- layer 2: H[32][128] @ W2[128][32] ----
        const int mt = w >> 1;
        f32x4 a2 = (f32x4){0.f, 0.f, 0.f, 0.f};
        #pragma unroll
        for (int kc = 0; kc < 4; ++kc) {
            const bf16x8 ah = *(const bf16x8*)&Hh[mt * 16 + lm][kc * 32 + kb * 8];
            const bf16x8 al = *(const bf16x8*)&Hl[mt * 16 + lm][kc * 32 + kb * 8];
            a2 = __builtin_amdgcn_mfma_f32_16x16x32_bf16(ah, W2r[kc][0], a2, 0, 0, 0);
            a2 = __builtin_amdgcn_mfma_f32_16x16x32_bf16(al, W2r[kc][0], a2, 0, 0, 0);
            a2 = __builtin_amdgcn_mfma_f32_16x16x32_bf16(ah, W2r[kc][1], a2, 0, 0, 0);
        }

        if (!fin) {
            // write new carry (cols 0-31 normally; 32-63 before combine, since
            // combine input is [node_tmp | summary])
            const int cb_ = (it == 15) ? 32 : 0;
            const int col = (w & 1) * 16 + lm;
            const float bias = b2c[col];
            #pragma unroll
            for (int rg = 0; rg < 4; ++rg) {
                const int row = mt * 16 + 4 * kb + rg;
                float v = a2[rg] + bias;
                v = v > 0.f ? v : 0.f;
                const __bf16 h = (__bf16)v;
                Xh[row][cb_ + col] = h;
                Xl[row][cb_ + col] = (__bf16)(v - (float)h);
            }
            if (pfmode) {
                const int dst = (pfmode == 2) ? 0 : 32;
                *(bf16x4*)&Xh[tt][dst + c4] = pfh;
                *(bf16x4*)&Xl[tt][dst + c4] = pfl;
            }
            __syncthreads();
        } else {
            // fused final linear: out = tree_sum . vfin + cfin
            const int col = (w & 1) * 16 + lm;
            const float bias = b2c[col];
            const float vf = vfin[col];
            float part[4];
            #pragma unroll
            for (int rg = 0; rg < 4; ++rg) {
                float v = a2[rg] + bias;
                v = v > 0.f ? v : 0.f;
                part[rg] = v * vf;
            }
            #pragma unroll
            for (int m = 1; m < 16; m <<= 1)
                #pragma unroll
                for (int rg = 0; rg < 4; ++rg)
                    part[rg] += __shfl_xor(part[rg], m, 64);
            if (lm == 0) {
                #pragma unroll
                for (int rg = 0; rg < 4; ++rg)
                    psum[w & 1][mt * 16 + 4 * kb + rg] = part[rg];
            }
            __syncthreads();
            if (tid < 32) out[base + tid] = cfin_s + psum[0][tid] + psum[1][tid];
        }
    }
}

extern "C" void kernel_launch(void* const* d_in, const int* in_sizes, int n_in,
                              void* d_out, int out_size, void* d_ws, size_t ws_size,
                              hipStream_t stream) {
    const int*   trees      = (const int*)d_in[0];
    const float* lstm       = (const float*)d_in[1];
    const float* embedding  = (const float*)d_in[4];
    const float* leaf_end_W = (const float*)d_in[5];
    const float* leaf_end_b = (const float*)d_in[6];
    const float* lc_W1 = (const float*)d_in[7];
    const float* lc_b1 = (const float*)d_in[8];
    const float* lc_W2 = (const float*)d_in[9];
    const float* lc_b2 = (const float*)d_in[10];
    const float* cs_W1 = (const float*)d_in[11];
    const float* cs_b1 = (const float*)d_in[12];
    const float* cs_W2 = (const float*)d_in[13];
    const float* cs_b2 = (const float*)d_in[14];
    const float* nf_W1 = (const float*)d_in[15];
    const float* nf_b1 = (const float*)d_in[16];
    const float* nf_W2 = (const float*)d_in[17];
    const float* nf_b2 = (const float*)d_in[18];
    const float* cb_W1 = (const float*)d_in[19];
    const float* cb_b1 = (const float*)d_in[20];
    const float* cb_W2 = (const float*)d_in[21];
    const float* cb_b2 = (const float*)d_in[22];
    const float* ff_W1 = (const float*)d_in[23];
    const float* ff_b1 = (const float*)d_in[24];
    const float* ff_W2 = (const float*)d_in[25];
    const float* ff_b2 = (const float*)d_in[26];
    const float* ts_W  = (const float*)d_in[27];
    const float* ts_b  = (const float*)d_in[28];

    char* ws = (char*)d_ws;
    __bf16* childrenH = (__bf16*)ws;                             // 8 MiB
    __bf16* childrenL = (__bf16*)(ws + 8388608);                 // 8 MiB
    __bf16* node_tmpH = (__bf16*)(ws + 16777216);                // 0.5 MiB
    __bf16* node_tmpL = (__bf16*)(ws + 17301504);                // 0.5 MiB
    __bf16* lcW1T    = (__bf16*)(ws + 17825792);
    __bf16* nfW1T    = (__bf16*)(ws + 17948672);
    __bf16* lcW2T    = (__bf16*)(ws + 18071552);
    __bf16* nfW2T    = (__bf16*)(ws + 18079744);
    __bf16* emb_bf   = (__bf16*)(ws + 18087936);
    float*  endvec   = (float*)(ws + 18094336);
    __bf16* csW1Th   = (__bf16*)(ws + 18094464);
    __bf16* csW1Tl   = (__bf16*)(ws + 18110848);
    __bf16* cbW1Th   = (__bf16*)(ws + 18127232);
    __bf16* cbW1Tl   = (__bf16*)(ws + 18143616);
    __bf16* csW2Th   = (__bf16*)(ws + 18160000);
    __bf16* csW2Tl   = (__bf16*)(ws + 18168192);
    __bf16* cbW2Th   = (__bf16*)(ws + 18176384);
    __bf16* cbW2Tl   = (__bf16*)(ws + 18184576);
    float*  vfin     = (float*)(ws + 18192768);
    float*  cfin     = (float*)(ws + 18192896);
    float*  outp     = (float*)d_out;

    prep_kernel<<<dim3(621), dim3(256), 0, stream>>>(
        embedding, leaf_end_W, leaf_end_b, lc_W1, lc_W2, nf_W1, nf_W2,
        cs_W1, cs_W2, cb_W1, cb_W2, ff_W1, ff_b1, ff_W2, ff_b2, ts_W, ts_b,
        lcW1T, nfW1T, lcW2T, nfW2T, emb_bf, endvec,
        csW1Th, csW1Tl, cbW1Th, cbW1Tl, csW2Th, csW2Tl, cbW2Th, cbW2Tl,
        vfin, cfin);

    mlp1_mfma<<<dim3(2176), dim3(256), 0, stream>>>(
        trees, lstm, lcW1T, nfW1T, lcW2T, nfW2T, emb_bf, endvec,
        lc_b1, lc_b2, nf_b1, nf_b2, childrenH, childrenL, node_tmpH, node_tmpL);

    scan_mfma<<<dim3(256), dim3(256), 0, stream>>>(
        childrenH, childrenL, node_tmpH, node_tmpL,
        csW1Th, csW1Tl, csW2Th, csW2Tl, cbW1Th, cbW1Tl, cbW2Th, cbW2Tl,
        cs_b1, cs_b2, cb_b1, cb_b2, vfin, cfin, outp);
}